// Round 8
// baseline (115.660 us; speedup 1.0000x reference)
//
#include <hip/hip_runtime.h>

// Problem constants: B=4, h=w=z=16 -> N=4096, C=128, Cq=16
#define NB     4
#define NN     4096
#define NC     128
#define NCQ    16
#define NROWS  (NB * NN)      // 16384
#define NSLICE 4
#define NBODY  32             // 32-key bodies per slice (1024 keys / slice)

typedef __attribute__((ext_vector_type(8)))  __bf16 bf16x8;
typedef __attribute__((ext_vector_type(4)))  float  f32x4;
typedef __attribute__((ext_vector_type(16))) float  f32x16;

#define MFMA16(a,b,c) __builtin_amdgcn_mfma_f32_16x16x32_bf16((a),(b),(c),0,0,0)
#define MFMA32(a,b,c) __builtin_amdgcn_mfma_f32_32x32x16_bf16((a),(b),(c),0,0,0)
#define LOG2E 1.44269504f
// Schraudolph bias for direct-to-bf16 exp2: bits(bf16(2^s)) ~= 128*s + 16248.66
#define SCH_BIAS 16248.66f

__device__ __forceinline__ f32x16 zero16() {
    f32x16 v;
    #pragma unroll
    for (int i = 0; i < 16; ++i) v[i] = 0.f;
    return v;
}

// Swizzled fragment layouts (lane = lh*32 + l31):
//  qswz: [batch][qb32][lane][8]  elem j = (LOG2E * Q)[32*qb32 + l31][ch = 8*lh + j]
//  kswz: [batch][kb32][lane][8]  elem j = K[32*kb32 + l31][ch = 8*lh + j]
//  vswz: [batch][kb16][cg][lane][8]
//        elem j = V^T[ch = 32*cg + l31][key = 16*kb16 + 4*lh + (j&3) + 8*(j>>2)]
//  Wp:   [oc][ch] bf16, oc 0..15 = Wb cols, 16..31 = Wc cols, 32..159 = Wd cols

// ---------------------------------------------------------------------------
// Kernel 0: one-shot W transpose+convert -> bf16 Wp[160][128].
// ---------------------------------------------------------------------------
__global__ __launch_bounds__(256) void wpre_kernel(
    const float* __restrict__ Wb, const float* __restrict__ Wc,
    const float* __restrict__ Wd, __bf16* __restrict__ Wp)
{
    int idx = blockIdx.x * 256 + threadIdx.x;   // 160*128 = 20480 exactly
    int oc = idx >> 7, ch = idx & 127;
    float v;
    if (oc < 16)      v = Wb[ch * 16 + oc];
    else if (oc < 32) v = Wc[ch * 16 + (oc - 16)];
    else              v = Wd[ch * 128 + (oc - 32)];
    Wp[idx] = (__bf16)v;
}

// ---------------------------------------------------------------------------
// Kernel 1: projections via MFMA. R8 delta: oc-SPLIT for occupancy — proj was
// 512 blocks = 2 waves/SIMD, latency-bound (≈15 us vs ~2 us traffic floor;
// R5's mild tweak moving the total 4 us corroborates latency sensitivity).
// Now 2 blocks per 32-row tile (grid 1024 = 4 blocks/CU = 4 waves/SIMD):
// half 0 -> osets 0..4, half 1 -> osets 5..9; within a block wave-group 0
// takes 3 osets, group 1 takes 2. Every (oset, row-half) computed exactly
// once; V/QK write paths byte-identical to the R2-verified kernel. x-tile
// staged twice per row-tile (2nd read is an L2 hit; HBM x traffic unchanged).
// ---------------------------------------------------------------------------
__global__ __launch_bounds__(256) void proj_kernel(
    const float* __restrict__ x,  const __bf16* __restrict__ Wp,
    __bf16* __restrict__ qswz, __bf16* __restrict__ kswz,
    __bf16* __restrict__ vswz)
{
    __shared__ __align__(16) __bf16 xsh[32 * 136];   // [row][136]
    __shared__ __align__(16) float  osb[4][16 * 17]; // per-wave transpose buffer

    const int  t    = threadIdx.x;
    const int  lane = t & 63, w = t >> 6;
    const int  q16  = lane & 15, quad = lane >> 4;
    const int  half = blockIdx.x & 1;                // oc half: osets h*5..h*5+4
    const long row0 = (long)(blockIdx.x >> 1) * 32;
    const int  batch = (int)(row0 >> 12);
    const int  nloc  = (int)(row0 & 4095);
    const int  rh   = w & 1;                         // row half (16 rows)
    const int  g    = w >> 1;                        // oset sub-group: 3 / 2
    const int  o0   = half * 5 + (g ? 3 : 0);        // first oset for this wave

    // ---- stage X tile (fp32 -> bf16), [32][128] -> xsh stride 136 ----
    #pragma unroll
    for (int i = 0; i < 4; ++i) {
        int idx = t + 256 * i;           // < 1024
        int r = idx >> 5, c4 = (idx & 31) * 4;
        float4 xv = *(const float4*)&x[(row0 + r) * NC + c4];
        union { __bf16 h[4]; uint2 u; } cv;
        cv.h[0] = (__bf16)xv.x; cv.h[1] = (__bf16)xv.y;
        cv.h[2] = (__bf16)xv.z; cv.h[3] = (__bf16)xv.w;
        *(uint2*)&xsh[r * 136 + c4] = cv.u;
    }
    __syncthreads();

    bf16x8 xf[4];
    #pragma unroll
    for (int kc = 0; kc < 4; ++kc)
        xf[kc] = *(const bf16x8*)&xsh[(rh * 16 + q16) * 136 + kc * 32 + quad * 8];

    const __bf16* wbase = Wp + (size_t)(o0 * 16 + q16) * 128 + quad * 8;
    bf16x8 wfb[4];
    #pragma unroll
    for (int kc = 0; kc < 4; ++kc)
        wfb[kc] = *(const bf16x8*)(wbase + kc * 32);

    float* osw = osb[w];
    auto body = [&](int oc_t, bool pre) {
        const int oset = o0 + oc_t;
        bf16x8 wfc[4];
        #pragma unroll
        for (int kc = 0; kc < 4; ++kc) wfc[kc] = wfb[kc];
        if (pre) {                       // prefetch next oset's fragments
            const __bf16* wn = wbase + (size_t)(oc_t + 1) * 2048;
            #pragma unroll
            for (int kc = 0; kc < 4; ++kc)
                wfb[kc] = *(const bf16x8*)(wn + kc * 32);
        }
        f32x4 acc = {0.f, 0.f, 0.f, 0.f};
        #pragma unroll
        for (int kc = 0; kc < 4; ++kc)
            acc = MFMA16(wfc[kc], xf[kc], acc);   // D'[oc][row]
        #pragma unroll
        for (int r = 0; r < 4; ++r)
            osw[(quad * 4 + r) * 17 + q16] = acc[r];   // osb[oc16][xrow16]

        if (oset >= 2) {
            int ch_l = lane & 15, lh_t = (lane >> 4) & 1, jh = lane >> 5;
            union { __bf16 h[4]; uint2 u; } cv;
            #pragma unroll
            for (int u2 = 0; u2 < 4; ++u2)
                cv.h[u2] = (__bf16)osw[ch_l * 17 + 8 * jh + 4 * lh_t + u2];
            int kb16 = (nloc >> 4) + rh;
            int cg   = (oset - 2) >> 1;
            int l31v = ((oset - 2) & 1) * 16 + ch_l;
            size_t off = ((((size_t)batch * 256 + kb16) * 4 + cg) << 9)
                       + (size_t)(lh_t * 32 + l31v) * 8 + jh * 4;
            *(uint2*)&vswz[off] = cv.u;
        } else if (lane < 32) {
            int xr = lane & 15, lh_t = lane >> 4;
            const float qsc = (oset == 0) ? LOG2E : 1.f;  // fold log2e into Q
            union { __bf16 h[8]; uint4 u; } cv;
            #pragma unroll
            for (int j = 0; j < 8; ++j)
                cv.h[j] = (__bf16)(osw[(8 * lh_t + j) * 17 + xr] * qsc);
            size_t off = ((((size_t)batch * 128 + (nloc >> 5)) * 64)
                       + (size_t)(lh_t * 32 + rh * 16 + xr)) * 8;
            __bf16* dst = (oset == 0) ? qswz : kswz;
            *(uint4*)&dst[off] = cv.u;
        }
    };
    if (g == 0) { body(0, true); body(1, true); body(2, false); }
    else        { body(0, true); body(1, false); }
}

// ---------------------------------------------------------------------------
// Kernel 2: flash attention — FROZEN from R7 (verified clean, fastest; sits
// just under the (256,4) register cliff — R3/R4 lesson: do not add pressure).
// ---------------------------------------------------------------------------
__global__ __launch_bounds__(256, 4) void attn_kernel(
    const __bf16* __restrict__ qswz, const __bf16* __restrict__ kswz,
    const __bf16* __restrict__ vswz, __bf16* __restrict__ Opart,
    float* __restrict__ lws)
{
    const int t    = threadIdx.x;
    const int lane = t & 63, w = t >> 6;
    const int l31 = lane & 31, lh = lane >> 5;
    const int bid   = blockIdx.x;
    const int xcd   = bid & 7;
    const int batch = xcd >> 1;              // constant per XCD
    const int spL   = xcd & 1;               // slice bit0, constant per XCD
    const int idx   = bid >> 3;              // 0..127
    const int qpair = idx & 63;              // 0..63
    const int spH   = idx >> 6;              // 0..1
    const int slice = (spH << 1) | spL;      // 0..3 (block-uniform)
    const int qb32  = qpair * 2 + (w >> 1);  // waves pair on q
    const int h     = w & 1;                 // channel half
    const int ks0   = slice * (32 * NBODY);  // first key of this slice

    // Q B-frag, fixed: n = q = 32*qb32 + l31, k = ch = 8*lh + j
    const bf16x8 qf = *(const bf16x8*)
        &qswz[(((size_t)batch * 128 + qb32) * 64 + lane) * 8];

    const __bf16* kptr = kswz + ((size_t)batch * 128 + (ks0 >> 5)) * 512 + lane * 8;
    const __bf16* vptr = vswz + ((size_t)batch * 256 + (ks0 >> 4)) * 2048
                       + h * 1024 + lane * 8;

    f32x16 O0 = zero16(), O1 = zero16();
    float  lacc = 0.f;
    const bool do_l = (h == 0);              // wave-uniform

    // prologue: body 0 K and V, then its scores
    bf16x8 kf = *(const bf16x8*)(kptr);
    bf16x8 va[4], vb[4];
    #pragma unroll
    for (int s = 0; s < 2; ++s) {            // body 0: kb16 = s, cg = 2h+ct
        va[2*s]     = *(const bf16x8*)(vptr + (size_t)(s * 4)     * 512);
        va[2*s + 1] = *(const bf16x8*)(vptr + (size_t)(s * 4 + 1) * 512);
    }
    f32x16 S = MFMA32(kf, qf, zero16());

// Body m (32 keys): S holds scores (computed at end of previous body).
// pk.f[0] = keys [32m,32m+16), pk.f[1] = [32m+16,32m+32) — verified against
// vswz key layout: bf16 j of pk.f[s] = S[8s+j] = key 16s+(j&3)+8*(j>>2)+4lh.
#define ATTN_BODY(M, CUR, NXT)                                                \
    {                                                                         \
        const int mn = ((M) + 1 < NBODY) ? (M) + 1 : (M);                     \
        kf = *(const bf16x8*)(kptr + (size_t)mn * 512);                       \
        _Pragma("unroll")                                                     \
        for (int s = 0; s < 2; ++s) {                                         \
            NXT[2*s]     = *(const bf16x8*)(vptr + (size_t)((2*mn+s)*4  )*512);\
            NXT[2*s + 1] = *(const bf16x8*)(vptr + (size_t)((2*mn+s)*4+1)*512);\
        }                                                                     \
        union { uint32_t u32[8]; bf16x8 f[2]; } pk;                           \
        _Pragma("unroll")                                                     \
        for (int i = 0; i < 8; ++i) {                                         \
            int e0 = (int)fmaf(S[2*i],   128.f, SCH_BIAS);                    \
            int e1 = (int)fmaf(S[2*i+1], 128.f, SCH_BIAS);                    \
            pk.u32[i] = __builtin_amdgcn_perm((uint32_t)e1,                   \
                                              (uint32_t)e0, 0x05040100u);     \
            if (do_l) {                                                       \
                union { uint32_t u; float fv; } c0, c1;                       \
                c0.u = (uint32_t)e0 << 16; c1.u = (uint32_t)e1 << 16;         \
                lacc += c0.fv + c1.fv;                                        \
            }                                                                 \
        }                                                                     \
        O0 = MFMA32(pk.f[0], CUR[0], O0);                                     \
        O1 = MFMA32(pk.f[0], CUR[1], O1);                                     \
        O0 = MFMA32(pk.f[1], CUR[2], O0);                                     \
        O1 = MFMA32(pk.f[1], CUR[3], O1);                                     \
        S = MFMA32(kf, qf, zero16());                                         \
    }

    for (int m = 0; m < NBODY; m += 2) {
        ATTN_BODY(m,     va, vb);
        ATTN_BODY(m + 1, vb, va);
    }
#undef ATTN_BODY

    const long base = (long)batch * NN;

    // ---- l: lane (l31,lh) summed 16 of each body's 32 keys for q = l31;
    //      partner lane (same l31, lh^1) holds the complement.
    float lfull = lacc + __shfl_xor(lacc, 32);
    if (h == 0 && lh == 0)
        lws[(size_t)slice * NROWS + base + qb32 * 32 + l31] = lfull;

    // ---- O partial -> Opart[slice][row][ch] bf16 (col = ch = 64h+32ct+l31) --
    #pragma unroll
    for (int ct = 0; ct < 2; ++ct) {
        f32x16 Ov = ct ? O1 : O0;
        #pragma unroll
        for (int r = 0; r < 16; ++r) {
            int q = qb32 * 32 + (r & 3) + 8 * (r >> 2) + 4 * lh;
            Opart[((size_t)slice * NROWS + base + q) * NC + 64 * h + 32 * ct + l31]
                = (__bf16)Ov[r];
        }
    }
}

// ---------------------------------------------------------------------------
// Kernel 3: combine 4 slice partials + epilogue: out = gamma*(SumO/Suml)+x.
// ---------------------------------------------------------------------------
__global__ __launch_bounds__(256) void combine_kernel(
    const __bf16* __restrict__ Op, const float* __restrict__ lws,
    const float* __restrict__ x, const float* __restrict__ gamma,
    float* __restrict__ out)
{
    __shared__ float gl[32];
    const int  t    = threadIdx.x;
    const long row0 = (long)blockIdx.x * 32;
    if (t < 32) {
        float l = 0.f;
        #pragma unroll
        for (int s = 0; s < NSLICE; ++s) l += lws[(size_t)s * NROWS + row0 + t];
        gl[t] = gamma[0] / l;
    }
    __syncthreads();
    const size_t s1 = (size_t)NROWS * NC;
    #pragma unroll
    for (int i = 0; i < 2; ++i) {
        int idx = t + 256 * i;                 // < 512 uint4 groups
        int r = idx >> 4, c8 = (idx & 15) * 8;
        size_t g = (size_t)(row0 + r) * NC + c8;
        float a[8];
        #pragma unroll
        for (int j = 0; j < 8; ++j) a[j] = 0.f;
        #pragma unroll
        for (int s = 0; s < NSLICE; ++s) {
            union { __bf16 h[8]; uint4 u; } av;
            av.u = *(const uint4*)&Op[s1 * s + g];
            #pragma unroll
            for (int j = 0; j < 8; ++j) a[j] += (float)av.h[j];
        }
        float sc = gl[r];
        float4 x0 = *(const float4*)&x[g];
        float4 x1 = *(const float4*)&x[g + 4];
        float4 o0, o1;
        o0.x = a[0] * sc + x0.x; o0.y = a[1] * sc + x0.y;
        o0.z = a[2] * sc + x0.z; o0.w = a[3] * sc + x0.w;
        o1.x = a[4] * sc + x1.x; o1.y = a[5] * sc + x1.y;
        o1.z = a[6] * sc + x1.z; o1.w = a[7] * sc + x1.w;
        *(float4*)&out[g]     = o0;
        *(float4*)&out[g + 4] = o1;
    }
}

// ---------------------------------------------------------------------------
extern "C" void kernel_launch(void* const* d_in, const int* in_sizes, int n_in,
                              void* d_out, int out_size, void* d_ws, size_t ws_size,
                              hipStream_t stream) {
    const float* x     = (const float*)d_in[0];
    const float* Wb    = (const float*)d_in[1];
    const float* Wc    = (const float*)d_in[2];
    const float* Wd    = (const float*)d_in[3];
    const float* gamma = (const float*)d_in[4];
    float*       out   = (float*)d_out;

    // ws: qswz .5M | kswz .5M | vswz 4M | Opart 4x4M bf16 | lws 256K | Wp 40K
    __bf16* qswz  = (__bf16*)d_ws;
    __bf16* kswz  = qswz + (size_t)NROWS * NCQ;
    __bf16* vswz  = kswz + (size_t)NROWS * NCQ;
    __bf16* Opart = vswz + (size_t)NB * NC * NN;
    float*  lws   = (float*)(Opart + (size_t)NSLICE * NROWS * NC);
    __bf16* Wp    = (__bf16*)(lws + (size_t)NSLICE * NROWS);

    wpre_kernel   <<<80, 256, 0, stream>>>(Wb, Wc, Wd, Wp);
    proj_kernel   <<<(NROWS / 32) * 2, 256, 0, stream>>>(x, Wp, qswz, kswz, vswz);
    attn_kernel   <<<NB * 64 * NSLICE, 256, 0, stream>>>(qswz, kswz, vswz, Opart, lws);
    combine_kernel<<<NROWS / 32, 256, 0, stream>>>(Opart, lws, x, gamma, out);
}

// Round 9
// 115.116 us; speedup vs baseline: 1.0047x; 1.0047x over previous
//
#include <hip/hip_runtime.h>

// Problem constants: B=4, h=w=z=16 -> N=4096, C=128, Cq=16
#define NB     4
#define NN     4096
#define NC     128
#define NCQ    16
#define NROWS  (NB * NN)      // 16384
#define NSLICE 4
#define NBODY  32             // 32-key bodies per slice (1024 keys / slice)

typedef __attribute__((ext_vector_type(8)))  __bf16 bf16x8;
typedef __attribute__((ext_vector_type(4)))  float  f32x4;
typedef __attribute__((ext_vector_type(16))) float  f32x16;

#define MFMA16(a,b,c) __builtin_amdgcn_mfma_f32_16x16x32_bf16((a),(b),(c),0,0,0)
#define MFMA32(a,b,c) __builtin_amdgcn_mfma_f32_32x32x16_bf16((a),(b),(c),0,0,0)
#define LOG2E 1.44269504f
// Schraudolph bias for direct-to-bf16 exp2: bits(bf16(2^s)) ~= 128*s + 16248.66
#define SCH_BIAS 16248.66f

__device__ __forceinline__ f32x16 zero16() {
    f32x16 v;
    #pragma unroll
    for (int i = 0; i < 16; ++i) v[i] = 0.f;
    return v;
}

// Swizzled fragment layouts (lane = lh*32 + l31):
//  qswz: [batch][qb32][lane][8]  elem j = (LOG2E * Q)[32*qb32 + l31][ch = 8*lh + j]
//  kswz: [batch][kb32][lane][8]  elem j = K[32*kb32 + l31][ch = 8*lh + j]
//  vswz: [batch][kb16][cg][lane][8]
//        elem j = V^T[ch = 32*cg + l31][key = 16*kb16 + 4*lh + (j&3) + 8*(j>>2)]
//  Wp:   [oc][ch] bf16, oc 0..15 = Wb cols, 16..31 = Wc cols, 32..159 = Wd cols

// ---------------------------------------------------------------------------
// Kernel 0: one-shot W transpose+convert -> bf16 Wp[160][128].
// ---------------------------------------------------------------------------
__global__ __launch_bounds__(256) void wpre_kernel(
    const float* __restrict__ Wb, const float* __restrict__ Wc,
    const float* __restrict__ Wd, __bf16* __restrict__ Wp)
{
    int idx = blockIdx.x * 256 + threadIdx.x;   // 160*128 = 20480 exactly
    int oc = idx >> 7, ch = idx & 127;
    float v;
    if (oc < 16)      v = Wb[ch * 16 + oc];
    else if (oc < 32) v = Wc[ch * 16 + (oc - 16)];
    else              v = Wd[ch * 128 + (oc - 32)];
    Wp[idx] = (__bf16)v;
}

// ---------------------------------------------------------------------------
// Kernel 1: projections via MFMA. R9 delta: 16-ROW tiles (row-split, not
// R8's failed oc-split). R8 post-mortem: oc-split doubled occupancy but also
// doubled the staging work (each x-tile staged twice) -> net regression;
// proj is staging-dominated. Row-split partitions the staging instead:
// 1024 blocks, each stages 16 rows (512 float4, 2/thread — half of R7's
// per-block stage, SAME total volume, zero duplication). All 4 waves share
// the 16 rows; osets partitioned 3/3/2/2 (w0:0-2, w1:3-5, w2:6-7, w3:8-9).
// Occupancy 2->4 blocks/CU; per-block serial depth {stage4+5 rounds} ->
// {stage2+3 rounds}. Write paths index-identical to the R2-verified kernel:
// kb16 = nloc>>4 (old +rh absorbed by finer grid); Q/K row-half bit from
// (nloc>>4)&1 instead of the wave bit.
// ---------------------------------------------------------------------------
__global__ __launch_bounds__(256) void proj_kernel(
    const float* __restrict__ x,  const __bf16* __restrict__ Wp,
    __bf16* __restrict__ qswz, __bf16* __restrict__ kswz,
    __bf16* __restrict__ vswz)
{
    __shared__ __align__(16) __bf16 xsh[16 * 136];   // [row][136]
    __shared__ __align__(16) float  osb[4][16 * 17]; // per-wave transpose buffer

    const int  t    = threadIdx.x;
    const int  lane = t & 63, w = t >> 6;
    const int  q16  = lane & 15, quad = lane >> 4;
    const long row0 = (long)blockIdx.x * 16;
    const int  batch = (int)(row0 >> 12);
    const int  nloc  = (int)(row0 & 4095);
    const int  kb16  = nloc >> 4;                    // block's 16-key group
    const int  rh16  = (nloc >> 4) & 1;              // half within the qb32 tile
    const int  o0    = (w < 2) ? w * 3 : 6 + (w - 2) * 2;  // osets 3/3/2/2

    // ---- stage X tile (fp32 -> bf16), [16][128] -> xsh stride 136 ----
    #pragma unroll
    for (int i = 0; i < 2; ++i) {
        int idx = t + 256 * i;           // < 512
        int r = idx >> 5, c4 = (idx & 31) * 4;
        float4 xv = *(const float4*)&x[(row0 + r) * NC + c4];
        union { __bf16 h[4]; uint2 u; } cv;
        cv.h[0] = (__bf16)xv.x; cv.h[1] = (__bf16)xv.y;
        cv.h[2] = (__bf16)xv.z; cv.h[3] = (__bf16)xv.w;
        *(uint2*)&xsh[r * 136 + c4] = cv.u;
    }
    __syncthreads();

    bf16x8 xf[4];
    #pragma unroll
    for (int kc = 0; kc < 4; ++kc)
        xf[kc] = *(const bf16x8*)&xsh[q16 * 136 + kc * 32 + quad * 8];

    const __bf16* wbase = Wp + (size_t)(o0 * 16 + q16) * 128 + quad * 8;
    bf16x8 wfb[4];
    #pragma unroll
    for (int kc = 0; kc < 4; ++kc)
        wfb[kc] = *(const bf16x8*)(wbase + kc * 32);

    float* osw = osb[w];
    auto body = [&](int oc_t, bool pre) {
        const int oset = o0 + oc_t;
        bf16x8 wfc[4];
        #pragma unroll
        for (int kc = 0; kc < 4; ++kc) wfc[kc] = wfb[kc];
        if (pre) {                       // prefetch next oset's fragments
            const __bf16* wn = wbase + (size_t)(oc_t + 1) * 2048;
            #pragma unroll
            for (int kc = 0; kc < 4; ++kc)
                wfb[kc] = *(const bf16x8*)(wn + kc * 32);
        }
        f32x4 acc = {0.f, 0.f, 0.f, 0.f};
        #pragma unroll
        for (int kc = 0; kc < 4; ++kc)
            acc = MFMA16(wfc[kc], xf[kc], acc);   // D'[oc][row]
        #pragma unroll
        for (int r = 0; r < 4; ++r)
            osw[(quad * 4 + r) * 17 + q16] = acc[r];   // osb[oc16][xrow16]

        if (oset >= 2) {
            int ch_l = lane & 15, lh_t = (lane >> 4) & 1, jh = lane >> 5;
            union { __bf16 h[4]; uint2 u; } cv;
            #pragma unroll
            for (int u2 = 0; u2 < 4; ++u2)
                cv.h[u2] = (__bf16)osw[ch_l * 17 + 8 * jh + 4 * lh_t + u2];
            int cg   = (oset - 2) >> 1;
            int l31v = ((oset - 2) & 1) * 16 + ch_l;
            size_t off = ((((size_t)batch * 256 + kb16) * 4 + cg) << 9)
                       + (size_t)(lh_t * 32 + l31v) * 8 + jh * 4;
            *(uint2*)&vswz[off] = cv.u;
        } else if (lane < 32) {
            int xr = lane & 15, lh_t = lane >> 4;
            const float qsc = (oset == 0) ? LOG2E : 1.f;  // fold log2e into Q
            union { __bf16 h[8]; uint4 u; } cv;
            #pragma unroll
            for (int j = 0; j < 8; ++j)
                cv.h[j] = (__bf16)(osw[(8 * lh_t + j) * 17 + xr] * qsc);
            size_t off = ((((size_t)batch * 128 + (nloc >> 5)) * 64)
                       + (size_t)(lh_t * 32 + rh16 * 16 + xr)) * 8;
            __bf16* dst = (oset == 0) ? qswz : kswz;
            *(uint4*)&dst[off] = cv.u;
        }
    };
    if (w < 2) { body(0, true); body(1, true); body(2, false); }
    else       { body(0, true); body(1, false); }
}

// ---------------------------------------------------------------------------
// Kernel 2: flash attention — FROZEN from R7 (verified clean, fastest; sits
// just under the (256,4) register cliff — R3/R4 lesson: do not add pressure).
// ---------------------------------------------------------------------------
__global__ __launch_bounds__(256, 4) void attn_kernel(
    const __bf16* __restrict__ qswz, const __bf16* __restrict__ kswz,
    const __bf16* __restrict__ vswz, __bf16* __restrict__ Opart,
    float* __restrict__ lws)
{
    const int t    = threadIdx.x;
    const int lane = t & 63, w = t >> 6;
    const int l31 = lane & 31, lh = lane >> 5;
    const int bid   = blockIdx.x;
    const int xcd   = bid & 7;
    const int batch = xcd >> 1;              // constant per XCD
    const int spL   = xcd & 1;               // slice bit0, constant per XCD
    const int idx   = bid >> 3;              // 0..127
    const int qpair = idx & 63;              // 0..63
    const int spH   = idx >> 6;              // 0..1
    const int slice = (spH << 1) | spL;      // 0..3 (block-uniform)
    const int qb32  = qpair * 2 + (w >> 1);  // waves pair on q
    const int h     = w & 1;                 // channel half
    const int ks0   = slice * (32 * NBODY);  // first key of this slice

    // Q B-frag, fixed: n = q = 32*qb32 + l31, k = ch = 8*lh + j
    const bf16x8 qf = *(const bf16x8*)
        &qswz[(((size_t)batch * 128 + qb32) * 64 + lane) * 8];

    const __bf16* kptr = kswz + ((size_t)batch * 128 + (ks0 >> 5)) * 512 + lane * 8;
    const __bf16* vptr = vswz + ((size_t)batch * 256 + (ks0 >> 4)) * 2048
                       + h * 1024 + lane * 8;

    f32x16 O0 = zero16(), O1 = zero16();
    float  lacc = 0.f;
    const bool do_l = (h == 0);              // wave-uniform

    // prologue: body 0 K and V, then its scores
    bf16x8 kf = *(const bf16x8*)(kptr);
    bf16x8 va[4], vb[4];
    #pragma unroll
    for (int s = 0; s < 2; ++s) {            // body 0: kb16 = s, cg = 2h+ct
        va[2*s]     = *(const bf16x8*)(vptr + (size_t)(s * 4)     * 512);
        va[2*s + 1] = *(const bf16x8*)(vptr + (size_t)(s * 4 + 1) * 512);
    }
    f32x16 S = MFMA32(kf, qf, zero16());

// Body m (32 keys): S holds scores (computed at end of previous body).
// pk.f[0] = keys [32m,32m+16), pk.f[1] = [32m+16,32m+32) — verified against
// vswz key layout: bf16 j of pk.f[s] = S[8s+j] = key 16s+(j&3)+8*(j>>2)+4lh.
#define ATTN_BODY(M, CUR, NXT)                                                \
    {                                                                         \
        const int mn = ((M) + 1 < NBODY) ? (M) + 1 : (M);                     \
        kf = *(const bf16x8*)(kptr + (size_t)mn * 512);                       \
        _Pragma("unroll")                                                     \
        for (int s = 0; s < 2; ++s) {                                         \
            NXT[2*s]     = *(const bf16x8*)(vptr + (size_t)((2*mn+s)*4  )*512);\
            NXT[2*s + 1] = *(const bf16x8*)(vptr + (size_t)((2*mn+s)*4+1)*512);\
        }                                                                     \
        union { uint32_t u32[8]; bf16x8 f[2]; } pk;                           \
        _Pragma("unroll")                                                     \
        for (int i = 0; i < 8; ++i) {                                         \
            int e0 = (int)fmaf(S[2*i],   128.f, SCH_BIAS);                    \
            int e1 = (int)fmaf(S[2*i+1], 128.f, SCH_BIAS);                    \
            pk.u32[i] = __builtin_amdgcn_perm((uint32_t)e1,                   \
                                              (uint32_t)e0, 0x05040100u);     \
            if (do_l) {                                                       \
                union { uint32_t u; float fv; } c0, c1;                       \
                c0.u = (uint32_t)e0 << 16; c1.u = (uint32_t)e1 << 16;         \
                lacc += c0.fv + c1.fv;                                        \
            }                                                                 \
        }                                                                     \
        O0 = MFMA32(pk.f[0], CUR[0], O0);                                     \
        O1 = MFMA32(pk.f[0], CUR[1], O1);                                     \
        O0 = MFMA32(pk.f[1], CUR[2], O0);                                     \
        O1 = MFMA32(pk.f[1], CUR[3], O1);                                     \
        S = MFMA32(kf, qf, zero16());                                         \
    }

    for (int m = 0; m < NBODY; m += 2) {
        ATTN_BODY(m,     va, vb);
        ATTN_BODY(m + 1, vb, va);
    }
#undef ATTN_BODY

    const long base = (long)batch * NN;

    // ---- l: lane (l31,lh) summed 16 of each body's 32 keys for q = l31;
    //      partner lane (same l31, lh^1) holds the complement.
    float lfull = lacc + __shfl_xor(lacc, 32);
    if (h == 0 && lh == 0)
        lws[(size_t)slice * NROWS + base + qb32 * 32 + l31] = lfull;

    // ---- O partial -> Opart[slice][row][ch] bf16 (col = ch = 64h+32ct+l31) --
    #pragma unroll
    for (int ct = 0; ct < 2; ++ct) {
        f32x16 Ov = ct ? O1 : O0;
        #pragma unroll
        for (int r = 0; r < 16; ++r) {
            int q = qb32 * 32 + (r & 3) + 8 * (r >> 2) + 4 * lh;
            Opart[((size_t)slice * NROWS + base + q) * NC + 64 * h + 32 * ct + l31]
                = (__bf16)Ov[r];
        }
    }
}

// ---------------------------------------------------------------------------
// Kernel 3: combine 4 slice partials + epilogue: out = gamma*(SumO/Suml)+x.
// ---------------------------------------------------------------------------
__global__ __launch_bounds__(256) void combine_kernel(
    const __bf16* __restrict__ Op, const float* __restrict__ lws,
    const float* __restrict__ x, const float* __restrict__ gamma,
    float* __restrict__ out)
{
    __shared__ float gl[32];
    const int  t    = threadIdx.x;
    const long row0 = (long)blockIdx.x * 32;
    if (t < 32) {
        float l = 0.f;
        #pragma unroll
        for (int s = 0; s < NSLICE; ++s) l += lws[(size_t)s * NROWS + row0 + t];
        gl[t] = gamma[0] / l;
    }
    __syncthreads();
    const size_t s1 = (size_t)NROWS * NC;
    #pragma unroll
    for (int i = 0; i < 2; ++i) {
        int idx = t + 256 * i;                 // < 512 uint4 groups
        int r = idx >> 4, c8 = (idx & 15) * 8;
        size_t g = (size_t)(row0 + r) * NC + c8;
        float a[8];
        #pragma unroll
        for (int j = 0; j < 8; ++j) a[j] = 0.f;
        #pragma unroll
        for (int s = 0; s < NSLICE; ++s) {
            union { __bf16 h[8]; uint4 u; } av;
            av.u = *(const uint4*)&Op[s1 * s + g];
            #pragma unroll
            for (int j = 0; j < 8; ++j) a[j] += (float)av.h[j];
        }
        float sc = gl[r];
        float4 x0 = *(const float4*)&x[g];
        float4 x1 = *(const float4*)&x[g + 4];
        float4 o0, o1;
        o0.x = a[0] * sc + x0.x; o0.y = a[1] * sc + x0.y;
        o0.z = a[2] * sc + x0.z; o0.w = a[3] * sc + x0.w;
        o1.x = a[4] * sc + x1.x; o1.y = a[5] * sc + x1.y;
        o1.z = a[6] * sc + x1.z; o1.w = a[7] * sc + x1.w;
        *(float4*)&out[g]     = o0;
        *(float4*)&out[g + 4] = o1;
    }
}

// ---------------------------------------------------------------------------
extern "C" void kernel_launch(void* const* d_in, const int* in_sizes, int n_in,
                              void* d_out, int out_size, void* d_ws, size_t ws_size,
                              hipStream_t stream) {
    const float* x     = (const float*)d_in[0];
    const float* Wb    = (const float*)d_in[1];
    const float* Wc    = (const float*)d_in[2];
    const float* Wd    = (const float*)d_in[3];
    const float* gamma = (const float*)d_in[4];
    float*       out   = (float*)d_out;

    // ws: qswz .5M | kswz .5M | vswz 4M | Opart 4x4M bf16 | lws 256K | Wp 40K
    __bf16* qswz  = (__bf16*)d_ws;
    __bf16* kswz  = qswz + (size_t)NROWS * NCQ;
    __bf16* vswz  = kswz + (size_t)NROWS * NCQ;
    __bf16* Opart = vswz + (size_t)NB * NC * NN;
    float*  lws   = (float*)(Opart + (size_t)NSLICE * NROWS * NC);
    __bf16* Wp    = (__bf16*)(lws + (size_t)NSLICE * NROWS);

    wpre_kernel   <<<80, 256, 0, stream>>>(Wb, Wc, Wd, Wp);
    proj_kernel   <<<NROWS / 16, 256, 0, stream>>>(x, Wp, qswz, kswz, vswz);
    attn_kernel   <<<NB * 64 * NSLICE, 256, 0, stream>>>(qswz, kswz, vswz, Opart, lws);
    combine_kernel<<<NROWS / 32, 256, 0, stream>>>(Opart, lws, x, gamma, out);
}